// Round 3
// baseline (159.187 us; speedup 1.0000x reference)
//
#include <hip/hip_runtime.h>

// PairwiseRankLoss: U=262144 users x G=64 items, K=2, MARGIN=0.3
// One 64-lane wave per user. DS-pipe-free design:
//  - median order stats via s_load of the yt row into SGPRs + ballot/popcount
//    rank capture (scalar pipe), a32 via DPP min-reduce
//  - top-2 rand per side via DPP max-reduce + ballot + readlane
// Deterministic two-stage reduction via d_ws.

static constexpr int kUsers = 262144;
static constexpr int kBlock = 256;                  // 4 waves / block
static constexpr int kGrid  = 2048;                 // 8 blocks / CU
static constexpr int kWavesPerBlock = kBlock / 64;
static constexpr int kTotalWaves = kGrid * kWavesPerBlock;  // 8192
static constexpr int kUsersPerWave = kUsers / kTotalWaves;  // 32
static constexpr float kMargin = 0.3f;

typedef float f32x16 __attribute__((ext_vector_type(16)));

template<int CTRL>
static __device__ __forceinline__ float dpp_mov(float x) {
    return __int_as_float(__builtin_amdgcn_update_dpp(
        __float_as_int(x), __float_as_int(x), CTRL, 0xF, 0xF, false));
}

// max across 64 lanes; valid in lane 63 (xor1,xor2,xor7,xor8 butterfly within
// rows of 16, then bcast15/bcast31 to fold rows upward). VALU-only, no DS.
static __device__ __forceinline__ float wavemax63(float x) {
    x = fmaxf(x, dpp_mov<0xB1>(x));    // quad_perm [1,0,3,2]  = xor1
    x = fmaxf(x, dpp_mov<0x4E>(x));    // quad_perm [2,3,0,1]  = xor2
    x = fmaxf(x, dpp_mov<0x141>(x));   // row_half_mirror      = xor7
    x = fmaxf(x, dpp_mov<0x128>(x));   // row_ror:8            = xor8
    x = fmaxf(x, dpp_mov<0x142>(x));   // row_bcast15
    x = fmaxf(x, dpp_mov<0x143>(x));   // row_bcast31
    return x;
}
static __device__ __forceinline__ float wavemin63(float x) {
    x = fminf(x, dpp_mov<0xB1>(x));
    x = fminf(x, dpp_mov<0x4E>(x));
    x = fminf(x, dpp_mov<0x141>(x));
    x = fminf(x, dpp_mov<0x128>(x));
    x = fminf(x, dpp_mov<0x142>(x));
    x = fminf(x, dpp_mov<0x143>(x));
    return x;
}

static __device__ __forceinline__ float readlane_f(float x, int l) {
    return __uint_as_float(__builtin_amdgcn_readlane(__float_as_uint(x), l));
}

// load 32 consecutive floats at wave-uniform address into SGPRs
static __device__ __forceinline__ void sload32(const float* p, f32x16& a, f32x16& b) {
    asm volatile(
        "s_load_dwordx16 %0, %2, 0x0\n\t"
        "s_load_dwordx16 %1, %2, 0x40\n\t"
        "s_waitcnt lgkmcnt(0)"
        : "=s"(a), "=s"(b)
        : "s"(p)
        : "memory");
}

__global__ __launch_bounds__(kBlock, 8)
void prl_user_kernel(const float* __restrict__ y_hat,
                     const float* __restrict__ y_true,
                     const float* __restrict__ rnd,
                     float* __restrict__ partials)
{
    const int lane = threadIdx.x & 63;
    const int wid  = (blockIdx.x * kBlock + threadIdx.x) >> 6;

    float acc = 0.0f;

    #pragma unroll 1
    for (int it = 0; it < kUsersPerWave; ++it) {
        const int u     = wid * kUsersPerWave + it;
        const int ubase = __builtin_amdgcn_readfirstlane(u << 6);

        const float yh = y_hat[ubase + lane];
        const float yt = y_true[ubase + lane];
        const float r  = rnd[ubase + lane];

        // ---- median: rank-capture via ballot/popcount over scalar pivots ----
        // a31 = value whose "count of smaller" == 31 (the 32nd smallest).
        float a31 = 0.0f;
        {
            f32x16 sa, sb;
            sload32(y_true + ubase, sa, sb);
            #pragma unroll
            for (int h = 0; h < 16; ++h) {
                const float sv = sa[h];
                if (__popcll(__ballot(yt < sv)) == 31) a31 = sv;
            }
            #pragma unroll
            for (int h = 0; h < 16; ++h) {
                const float sv = sb[h];
                if (__popcll(__ballot(yt < sv)) == 31) a31 = sv;
            }
            sload32(y_true + ubase + 32, sa, sb);
            #pragma unroll
            for (int h = 0; h < 16; ++h) {
                const float sv = sa[h];
                if (__popcll(__ballot(yt < sv)) == 31) a31 = sv;
            }
            #pragma unroll
            for (int h = 0; h < 16; ++h) {
                const float sv = sb[h];
                if (__popcll(__ballot(yt < sv)) == 31) a31 = sv;
            }
        }
        // a32 = smallest value strictly greater than a31 (33rd smallest)
        const float cand = (yt > a31) ? yt : 3.0e38f;
        const float a32  = readlane_f(wavemin63(cand), 63);
        const float med  = 0.5f * (a31 + a32);
        const bool  pos  = (yt > med);          // bit-exact vs reference mask

        // ---- top-2 rand per side via DPP max + ballot; gather via readlane --
        float P0, P1, N0, N1;
        #pragma unroll
        for (int side = 0; side < 2; ++side) {
            const bool m = (side == 0) ? pos : !pos;
            float key = m ? r : -2.0f;          // r in [0,1): -2 acts as -inf
            const float smx = readlane_f(wavemax63(key), 63);
            const int w1 = __builtin_ctzll(__ballot(key == smx));  // low idx tie
            const float A0 = readlane_f(yh, w1);
            key = (lane == w1) ? -3.0f : key;   // exclude winner
            const float smx2 = readlane_f(wavemax63(key), 63);
            const int w2 = __builtin_ctzll(__ballot(key == smx2));
            const float A1 = readlane_f(yh, w2);
            if (side == 0) { P0 = A0; P1 = A1; }
            else           { N0 = A0; N1 = A1; }
        }

        // ---- 2x2 hinge mean ----
        float s = 0.0f;
        s += fmaxf(kMargin - (P0 - N0), 0.0f);
        s += fmaxf(kMargin - (P0 - N1), 0.0f);
        s += fmaxf(kMargin - (P1 - N0), 0.0f);
        s += fmaxf(kMargin - (P1 - N1), 0.0f);
        acc += 0.25f * s;
    }

    // block partial (acc is wave-uniform; take lane 0 of each wave)
    __shared__ float wsum[kWavesPerBlock];
    if (lane == 0) wsum[threadIdx.x >> 6] = acc;
    __syncthreads();
    if (threadIdx.x == 0) {
        float t = 0.0f;
        #pragma unroll
        for (int i = 0; i < kWavesPerBlock; ++i) t += wsum[i];
        partials[blockIdx.x] = t;
    }
}

__global__ void prl_reduce_kernel(const float* __restrict__ partials,
                                  float* __restrict__ out)
{
    // one block of 256 threads reduces kGrid partials in a fixed order
    float t = 0.0f;
    for (int i = threadIdx.x; i < kGrid; i += 256) t += partials[i];
    #pragma unroll
    for (int s = 32; s > 0; s >>= 1) t += __shfl_xor(t, s);
    __shared__ float ws[4];
    if ((threadIdx.x & 63) == 0) ws[threadIdx.x >> 6] = t;
    __syncthreads();
    if (threadIdx.x == 0) {
        out[0] = (ws[0] + ws[1] + ws[2] + ws[3]) * (1.0f / (float)kUsers);
    }
}

extern "C" void kernel_launch(void* const* d_in, const int* in_sizes, int n_in,
                              void* d_out, int out_size, void* d_ws, size_t ws_size,
                              hipStream_t stream) {
    const float* y_hat  = (const float*)d_in[0];
    const float* y_true = (const float*)d_in[1];
    const float* rnd    = (const float*)d_in[2];
    // d_in[3] = user_idx: contiguous equal-size segments -> never read
    float* partials = (float*)d_ws;          // kGrid floats = 8 KiB scratch
    float* out      = (float*)d_out;

    hipLaunchKernelGGL(prl_user_kernel, dim3(kGrid), dim3(kBlock), 0, stream,
                       y_hat, y_true, rnd, partials);
    hipLaunchKernelGGL(prl_reduce_kernel, dim3(1), dim3(256), 0, stream,
                       partials, out);
}